// Round 1
// baseline (2187.512 us; speedup 1.0000x reference)
//
#include <hip/hip_runtime.h>
#include <hip/hip_bf16.h>
#include <cstddef>

#define B_ 2
#define C_ 16
#define H_ 128
#define W_ 128
#define M_ 9
#define ND_ 9
#define MC_ 144
#define HID_ 18
#define OUT_ 150
#define EPS_ 1e-5f

// ---- workspace layout (float offsets) ----
#define OFF_P     0          // [B][144] pooled means                 (288)
#define OFF_XG    512        // [B][9]  global-attention out          (18)
#define OFF_W1F   1024       // conv1 w, BN1-folded: [mc][kw][kh][kdd][18] (69984)
#define OFF_B1F   71040      // [18]
#define OFF_W2F   71104      // conv2 w, BN2-folded: [c][tap][9]      (4374)
#define OFF_B2F   75520      // [9]
#define OFF_CLWT  75584      // cl_w transposed [mc][150]             (21600)
#define OFF_F     98304      // F[b][m][kdd][h][wpp=130][20pad]       (17,971,200)
#define OFF_HBUF  18069504   // h after relu: [b][h][w][d][18]        (5,308,416)
#define OFF_WEI   23377920   // sigmoid attention: [b][h][w][d][9]    (2,654,208)
#define OFF_GB_BYTES (26032128ull*4ull)  // G bf16 [b][m][h][w'][150] (44,236,800 bf16)
// total ws: ~184 MB

// ---------------- K1: pooled mean of cost volume (global-attn input) ----------
__global__ __launch_bounds__(256) void k_pool(const float* __restrict__ x,
                                              float* __restrict__ ws) {
  int bid = blockIdx.x;                 // 0..287 = b*144+mc
  int b = bid / MC_, mc = bid % MC_;
  int m = mc / C_, c = mc % C_;
  int sm = m - 4;
  const float* xb = x + (size_t)(b*C_ + c)*H_*W_*M_;
  float acc = 0.f;
  for (int idx = threadIdx.x; idx < H_*W_*ND_; idx += 256) {
    int w = idx & 127;
    int t = idx >> 7;
    int d = t % 9;
    int h = t / 9;
    int wc = w + (d - 4)*sm;
    if (wc >= 0 && wc < W_) acc += xb[(h*W_ + wc)*M_ + m];
  }
  __shared__ float red[256];
  red[threadIdx.x] = acc;
  __syncthreads();
  for (int s = 128; s > 0; s >>= 1) {
    if ((int)threadIdx.x < s) red[threadIdx.x] += red[threadIdx.x + s];
    __syncthreads();
  }
  if (threadIdx.x == 0)
    ws[OFF_P + b*MC_ + mc] = red[0] * (1.f/(float)(H_*W_*ND_));
}

// ---------------- K2: fold BN into conv weights; transpose layouts ------------
__global__ __launch_bounds__(256) void k_repack(
    const float* __restrict__ w1, const float* __restrict__ b1,
    const float* __restrict__ g1, const float* __restrict__ be1,
    const float* __restrict__ m1, const float* __restrict__ v1,
    const float* __restrict__ w2, const float* __restrict__ b2,
    const float* __restrict__ g2, const float* __restrict__ be2,
    const float* __restrict__ m2, const float* __restrict__ v2,
    const float* __restrict__ clw, float* __restrict__ ws) {
  int id = blockIdx.x*256 + threadIdx.x;
  if (id < 69984) {                      // w1f: [mc][kw][kh][kdd][o]
    int o   = id % 18;
    int kdd = (id/18) % 3;
    int kh  = (id/54) % 3;
    int kw  = (id/162) % 3;
    int mc  = id/486;
    float s = g1[o] / sqrtf(v1[o] + EPS_);
    ws[OFF_W1F + id] = w1[(o*MC_ + mc)*27 + kh*9 + kw*3 + kdd] * s;
    return;
  }
  id -= 69984;
  if (id < 18) {
    float s = g1[id]/sqrtf(v1[id]+EPS_);
    ws[OFF_B1F + id] = (b1[id]-m1[id])*s + be1[id];
    return;
  }
  id -= 18;
  if (id < 4374) {                       // w2f: [c][tap][i]
    int i = id % 9, tap = (id/9) % 27, c = id/243;
    float s = g2[i]/sqrtf(v2[i]+EPS_);
    ws[OFF_W2F + id] = w2[(i*HID_ + c)*27 + tap] * s;
    return;
  }
  id -= 4374;
  if (id < 9) {
    float s = g2[id]/sqrtf(v2[id]+EPS_);
    ws[OFF_B2F + id] = (b2[id]-m2[id])*s + be2[id];
    return;
  }
  id -= 9;
  if (id < 21600) {                      // clwT: [mc][oc]
    int oc = id % OUT_, mc = id / OUT_;
    ws[OFF_CLWT + id] = clw[oc*MC_ + mc];
  }
}

// ---------------- K3: global attention branch (1x1x1 volume => center taps) ---
__global__ __launch_bounds__(64) void k_ga(
    const float* __restrict__ gw1, const float* __restrict__ gb1,
    const float* __restrict__ gg1, const float* __restrict__ gbe1,
    const float* __restrict__ gm1, const float* __restrict__ gv1,
    const float* __restrict__ gw2, const float* __restrict__ gb2,
    const float* __restrict__ gg2, const float* __restrict__ gbe2,
    const float* __restrict__ gm2, const float* __restrict__ gv2,
    float* __restrict__ ws) {
  __shared__ float gl[B_*HID_];
  int t = threadIdx.x;
  if (t < B_*HID_) {
    int b = t / HID_, j = t % HID_;
    float acc = gb1[j];
    for (int ch = 0; ch < MC_; ch++)
      acc += gw1[(j*MC_ + ch)*27 + 13] * ws[OFF_P + b*MC_ + ch];
    float s = gg1[j]/sqrtf(gv1[j]+EPS_);
    gl[t] = fmaxf((acc - gm1[j])*s + gbe1[j], 0.f);
  }
  __syncthreads();
  if (t < B_*M_) {
    int b = t / M_, i = t % M_;
    float acc = gb2[i];
    for (int j = 0; j < HID_; j++)
      acc += gw2[(i*HID_ + j)*27 + 13] * gl[b*HID_ + j];
    float s = gg2[i]/sqrtf(gv2[i]+EPS_);
    ws[OFF_XG + b*M_ + i] = (acc - gm2[i])*s + gbe2[i];
  }
}

// ---------------- K4: F[b][m][kdd][h][w''][o] = per-(m,kdd) 2D 3x3 conv of x --
// F(w'') = sum_{c,kh,kw} w1f * x[c, h+kh-1, w''+kw-1, m], x zero-padded.
__global__ __launch_bounds__(256) void k_F(const float* __restrict__ x,
                                           float* __restrict__ ws) {
  int h0 = blockIdx.x * 4;
  int m  = blockIdx.y;
  int b  = blockIdx.z;
  __shared__ float xt[C_*132*6];        // [c][col+2 (0..131)][hrow 0..5]
  for (int e = threadIdx.x; e < C_*132*6; e += 256) {
    int hh = e % 6;
    int cc = (e/6) % 132;
    int c  = e / 792;
    int row = h0 - 1 + hh;
    int col = cc - 2;
    float v = 0.f;
    if (row >= 0 && row < H_ && col >= 0 && col < W_)
      v = x[(((size_t)(b*C_ + c)*H_ + row)*W_ + col)*M_ + m];
    xt[e] = v;
  }
  __syncthreads();
  const float* w1f = ws + OFF_W1F;
  float* Fb = ws + OFF_F + (size_t)(b*M_ + m)*3*H_*130*20;
  for (int pp = threadIdx.x; pp < 130*18; pp += 256) {
    int o   = pp % 18;
    int wpp = pp / 18;                  // w'' = wpp-1 in [-1,128]
    float acc[3][4] = {};
    for (int c = 0; c < C_; c++) {
      int wb = (m*C_ + c)*486 + o;
      #pragma unroll
      for (int kw = 0; kw < 3; kw++) {
        const float* xp = xt + (c*132 + wpp + kw)*6;   // col = w''+kw-1
        float xv[6];
        #pragma unroll
        for (int q = 0; q < 6; q++) xv[q] = xp[q];
        const float* wp = w1f + wb + kw*162;
        #pragma unroll
        for (int kh = 0; kh < 3; kh++)
          #pragma unroll
          for (int kdd = 0; kdd < 3; kdd++) {
            float wv = wp[kh*54 + kdd*18];
            #pragma unroll
            for (int hh = 0; hh < 4; hh++)
              acc[kdd][hh] += wv * xv[hh + kh];
          }
      }
    }
    #pragma unroll
    for (int kdd = 0; kdd < 3; kdd++)
      #pragma unroll
      for (int hh = 0; hh < 4; hh++)
        Fb[(((size_t)kdd*H_ + (h0+hh))*130 + wpp)*20 + o] = acc[kdd][hh];
  }
}

// ---------------- K5: conv1 = gather-sum of F (+edge fix) + BN bias + ReLU ----
__global__ __launch_bounds__(256) void k_comb1(const float* __restrict__ x,
                                               float* __restrict__ ws) {
  int p = blockIdx.x*256 + threadIdx.x;  // flat point ((b*H+h)*W+w)*9+d
  int d = p % 9;
  int w = (p / 9) % W_;
  int h = (p / (9*W_)) % H_;
  int b = p / (9*W_*H_);
  const float* Fq = ws + OFF_F;
  float acc[18];
  #pragma unroll
  for (int o = 0; o < 18; o++) acc[o] = ws[OFF_B1F + o];
  for (int m = 0; m < M_; m++) {
    int sm = m - 4;
    #pragma unroll
    for (int kdd = 0; kdd < 3; kdd++) {
      int dp = d + kdd - 1;
      if (dp < 0 || dp >= ND_) continue;
      int wg = w + (dp - 4)*sm;
      if (wg < -1 || wg > 128) continue;          // F is zero outside
      const float* Fr = Fq + (((size_t)((b*M_+m)*3 + kdd)*H_ + h)*130 + (wg+1))*20;
      float4 a0 = *(const float4*)(Fr);
      float4 a1 = *(const float4*)(Fr + 4);
      float4 a2 = *(const float4*)(Fr + 8);
      float4 a3 = *(const float4*)(Fr + 12);
      float2 a4 = *(const float2*)(Fr + 16);
      acc[0]+=a0.x; acc[1]+=a0.y; acc[2]+=a0.z; acc[3]+=a0.w;
      acc[4]+=a1.x; acc[5]+=a1.y; acc[6]+=a1.z; acc[7]+=a1.w;
      acc[8]+=a2.x; acc[9]+=a2.y; acc[10]+=a2.z; acc[11]+=a2.w;
      acc[12]+=a3.x; acc[13]+=a3.y; acc[14]+=a3.z; acc[15]+=a3.w;
      acc[16]+=a4.x; acc[17]+=a4.y;
    }
  }
  // w-padding edge correction: conv zero-pads BEFORE the disparity shift.
  if (w == 0 || w == 127) {
    int kwe = (w == 0) ? 0 : 2;
    const float* w1f = ws + OFF_W1F;
    for (int m = 0; m < M_; m++) {
      int sm = m - 4;
      for (int kdd = 0; kdd < 3; kdd++) {
        int dp = d + kdd - 1;
        if (dp < 0 || dp >= ND_) continue;
        int col = w + (dp - 4)*sm + kwe - 1;
        if (col < 0 || col >= W_) continue;
        for (int c = 0; c < C_; c++) {
          const float* wpb = w1f + (m*C_ + c)*486 + kwe*162 + kdd*18;
          for (int kh = 0; kh < 3; kh++) {
            int row = h + kh - 1;
            if (row < 0 || row >= H_) continue;
            float xv = x[(((size_t)(b*C_ + c)*H_ + row)*W_ + col)*M_ + m];
            const float* wp2 = wpb + kh*54;
            #pragma unroll
            for (int o = 0; o < 18; o++) acc[o] -= wp2[o] * xv;
          }
        }
      }
    }
  }
  float2* hb2 = (float2*)(ws + OFF_HBUF + (size_t)p*18);
  #pragma unroll
  for (int q = 0; q < 9; q++)
    hb2[q] = make_float2(fmaxf(acc[2*q], 0.f), fmaxf(acc[2*q+1], 0.f));
}

// ---------------- K6: conv2 (18->9, 3x3x3) + BN + x_g + sigmoid -> wei --------
__global__ __launch_bounds__(576) void k_conv2(float* __restrict__ ws) {
  int w0 = blockIdx.x * 8;
  int h0 = blockIdx.y * 8;
  int b  = blockIdx.z;
  int t  = threadIdx.x;
  int lh = t / 72;
  int lw = (t / 9) % 8;
  int d  = t % 9;
  __shared__ float ht[9900];            // [hh 10][ww 10][dd 11][cc 9]
  const float* hbuf = ws + OFF_HBUF;
  const float* w2f  = ws + OFF_W2F;
  float acc[9] = {};
  for (int c0 = 0; c0 < 18; c0 += 9) {
    __syncthreads();
    for (int e = t; e < 9900; e += 576) {
      int cc = e % 9;
      int dd = (e/9) % 11;
      int ww = (e/99) % 10;
      int hh = e / 990;
      int gh = h0 - 1 + hh, gw = w0 - 1 + ww, gd = dd - 1;
      float v = 0.f;
      if (gh >= 0 && gh < H_ && gw >= 0 && gw < W_ && gd >= 0 && gd < ND_)
        v = hbuf[((size_t)((b*H_ + gh)*W_ + gw)*9 + gd)*18 + c0 + cc];
      ht[e] = v;
    }
    __syncthreads();
    for (int cc = 0; cc < 9; cc++) {
      #pragma unroll
      for (int kh = 0; kh < 3; kh++)
        #pragma unroll
        for (int kw = 0; kw < 3; kw++)
          #pragma unroll
          for (int kdd = 0; kdd < 3; kdd++) {
            float v = ht[(((lh+kh)*10 + (lw+kw))*11 + (d+kdd))*9 + cc];
            const float* wp = w2f + ((c0+cc)*27 + kh*9 + kw*3 + kdd)*9;
            #pragma unroll
            for (int i = 0; i < 9; i++) acc[i] += wp[i] * v;
          }
    }
  }
  int h = h0 + lh, w = w0 + lw;
  float* wei = ws + OFF_WEI + ((size_t)((b*H_ + h)*W_ + w)*9 + d)*9;
  const float* xg = ws + OFF_XG + b*M_;
  #pragma unroll
  for (int i = 0; i < 9; i++) {
    float y = acc[i] + ws[OFF_B2F + i] + xg[i];
    wei[i] = 1.f / (1.f + expf(-y));
  }
}

// ---------------- K7: G[b][m][h][w'][oc] = sum_c clw[oc][mc]*x[c,h,w',m] ------
__global__ __launch_bounds__(192) void k_G(const float* __restrict__ x,
                                           const float* __restrict__ ws,
                                           __hip_bfloat16* __restrict__ Gb) {
  int h = blockIdx.x, m = blockIdx.y, b = blockIdx.z;
  int oc = threadIdx.x;
  if (oc >= OUT_) return;
  const float* clwT = ws + OFF_CLWT;
  float wreg[C_];
  #pragma unroll
  for (int c = 0; c < C_; c++) wreg[c] = clwT[(m*C_ + c)*OUT_ + oc];
  __hip_bfloat16* Gr = Gb + ((size_t)(b*M_ + m)*H_ + h)*W_*OUT_;
  for (int wp = 0; wp < W_; wp++) {
    float acc = 0.f;
    #pragma unroll
    for (int c = 0; c < C_; c++) {
      float xv = x[(((size_t)(b*C_ + c)*H_ + h)*W_ + wp)*M_ + m];
      acc += wreg[c] * xv;
    }
    Gr[wp*OUT_ + oc] = __float2bfloat16(acc);
  }
}

// ---------------- K8: out = cl_b + sum_m wei[m]*G[m][w+s][oc], coalesced write -
__global__ __launch_bounds__(192) void k_last(const float* __restrict__ ws,
                                              const __hip_bfloat16* __restrict__ Gb,
                                              const float* __restrict__ clb,
                                              float* __restrict__ out) {
  int w0 = blockIdx.x * 8;
  int h  = blockIdx.y;
  int b  = blockIdx.z;
  int t  = threadIdx.x;
  __shared__ float lout[8*9*152];       // [wi][d][oc pad 152]
  int oc = t;
  if (oc < OUT_) {
    float cb = clb[oc];
    const float* wei = ws + OFF_WEI;
    for (int wi = 0; wi < 8; wi++) {
      int w = w0 + wi;
      const float* wv = wei + (size_t)((b*H_ + h)*W_ + w)*9*9;
      for (int d = 0; d < 9; d++) {
        float acc = cb;
        #pragma unroll
        for (int m = 0; m < 9; m++) {
          int wg = w + (d - 4)*(m - 4);
          if (wg >= 0 && wg < W_) {
            float g = __bfloat162float(
                Gb[(((size_t)(b*M_ + m)*H_ + h)*W_ + wg)*OUT_ + oc]);
            acc += wv[d*9 + m] * g;
          }
        }
        lout[(wi*9 + d)*152 + oc] = acc;
      }
    }
  }
  __syncthreads();
  for (int e = t; e < 8*OUT_; e += 192) {
    int oc2 = e / 8;
    int wi  = e % 8;
    float* op = out + (((size_t)(b*OUT_ + oc2)*H_ + h)*W_ + (w0 + wi))*9;
    #pragma unroll
    for (int dd = 0; dd < 9; dd++)
      op[dd] = lout[(wi*9 + dd)*152 + oc2];
  }
}

extern "C" void kernel_launch(void* const* d_in, const int* in_sizes, int n_in,
                              void* d_out, int out_size, void* d_ws, size_t ws_size,
                              hipStream_t stream) {
  const float* x       = (const float*)d_in[0];
  const float* la_w1   = (const float*)d_in[1];
  const float* la_b1   = (const float*)d_in[2];
  const float* la_g1   = (const float*)d_in[3];
  const float* la_be1  = (const float*)d_in[4];
  const float* la_m1   = (const float*)d_in[5];
  const float* la_v1   = (const float*)d_in[6];
  const float* la_w2   = (const float*)d_in[7];
  const float* la_b2   = (const float*)d_in[8];
  const float* la_g2   = (const float*)d_in[9];
  const float* la_be2  = (const float*)d_in[10];
  const float* la_m2   = (const float*)d_in[11];
  const float* la_v2   = (const float*)d_in[12];
  const float* ga_w1   = (const float*)d_in[13];
  const float* ga_b1   = (const float*)d_in[14];
  const float* ga_g1   = (const float*)d_in[15];
  const float* ga_be1  = (const float*)d_in[16];
  const float* ga_m1   = (const float*)d_in[17];
  const float* ga_v1   = (const float*)d_in[18];
  const float* ga_w2   = (const float*)d_in[19];
  const float* ga_b2   = (const float*)d_in[20];
  const float* ga_g2   = (const float*)d_in[21];
  const float* ga_be2  = (const float*)d_in[22];
  const float* ga_m2   = (const float*)d_in[23];
  const float* ga_v2   = (const float*)d_in[24];
  const float* cl_w    = (const float*)d_in[25];
  const float* cl_b    = (const float*)d_in[26];

  float* ws = (float*)d_ws;
  __hip_bfloat16* Gb = (__hip_bfloat16*)((char*)d_ws + OFF_GB_BYTES);
  float* out = (float*)d_out;

  k_pool  <<<288, 256, 0, stream>>>(x, ws);
  k_repack<<<375, 256, 0, stream>>>(la_w1, la_b1, la_g1, la_be1, la_m1, la_v1,
                                    la_w2, la_b2, la_g2, la_be2, la_m2, la_v2,
                                    cl_w, ws);
  k_ga    <<<1, 64, 0, stream>>>(ga_w1, ga_b1, ga_g1, ga_be1, ga_m1, ga_v1,
                                 ga_w2, ga_b2, ga_g2, ga_be2, ga_m2, ga_v2, ws);
  k_F     <<<dim3(32, 9, 2), 256, 0, stream>>>(x, ws);
  k_comb1 <<<1152, 256, 0, stream>>>(x, ws);
  k_conv2 <<<dim3(16, 16, 2), 576, 0, stream>>>(ws);
  k_G     <<<dim3(128, 9, 2), 192, 0, stream>>>(x, ws, Gb);
  k_last  <<<dim3(16, 128, 2), 192, 0, stream>>>(ws, Gb, cl_b, out);
}

// Round 2
// 1409.066 us; speedup vs baseline: 1.5525x; 1.5525x over previous
//
#include <hip/hip_runtime.h>
#include <hip/hip_bf16.h>
#include <cstddef>

#define B_ 2
#define C_ 16
#define H_ 128
#define W_ 128
#define M_ 9
#define ND_ 9
#define MC_ 144
#define HID_ 18
#define OUT_ 150
#define GOC_ 152          // padded oc stride for G (8B-aligned quads)
#define EPS_ 1e-5f

// ---- workspace layout (float offsets) ----
#define OFF_P     0          // [B][144] pooled means                 (288)
#define OFF_XG    512        // [B][9]  global-attention out          (18)
#define OFF_W1F   1024       // conv1 w, BN1-folded: [mc][kw][kh][kdd][18] (69984)
#define OFF_B1F   71040      // [18]
#define OFF_W2F   71104      // conv2 w, BN2-folded: [c][tap][9]      (4374)
#define OFF_B2F   75520      // [9]
#define OFF_CLWT  75584      // cl_w transposed [mc][150]             (21600)
#define OFF_F     98304      // F[b][m][kdd][h][wpp=130][20pad]       (17,971,200)
#define OFF_HBUF  18069504   // h after relu: [b][h][w][d][18]        (5,308,416)
#define OFF_WEI   23377920   // sigmoid attention: [b][h][w][d][9]    (2,654,208)
// G (bf16) overlays F+HBUF: both are dead before k_G runs.
// G[b][h][m][w'][152] = 44,777,472 bf16 = 89.6 MB; ends well before OFF_WEI.
#define OFF_GB_BYTES (98304ull*4ull)

// ---------------- K1: pooled mean of cost volume (global-attn input) ----------
__global__ __launch_bounds__(256) void k_pool(const float* __restrict__ x,
                                              float* __restrict__ ws) {
  int bid = blockIdx.x;                 // 0..287 = b*144+mc
  int b = bid / MC_, mc = bid % MC_;
  int m = mc / C_, c = mc % C_;
  int sm = m - 4;
  const float* xb = x + (size_t)(b*C_ + c)*H_*W_*M_;
  float acc = 0.f;
  for (int idx = threadIdx.x; idx < H_*W_*ND_; idx += 256) {
    int w = idx & 127;
    int t = idx >> 7;
    int d = t % 9;
    int h = t / 9;
    int wc = w + (d - 4)*sm;
    if (wc >= 0 && wc < W_) acc += xb[(h*W_ + wc)*M_ + m];
  }
  __shared__ float red[256];
  red[threadIdx.x] = acc;
  __syncthreads();
  for (int s = 128; s > 0; s >>= 1) {
    if ((int)threadIdx.x < s) red[threadIdx.x] += red[threadIdx.x + s];
    __syncthreads();
  }
  if (threadIdx.x == 0)
    ws[OFF_P + b*MC_ + mc] = red[0] * (1.f/(float)(H_*W_*ND_));
}

// ---------------- K2: fold BN into conv weights; transpose layouts ------------
__global__ __launch_bounds__(256) void k_repack(
    const float* __restrict__ w1, const float* __restrict__ b1,
    const float* __restrict__ g1, const float* __restrict__ be1,
    const float* __restrict__ m1, const float* __restrict__ v1,
    const float* __restrict__ w2, const float* __restrict__ b2,
    const float* __restrict__ g2, const float* __restrict__ be2,
    const float* __restrict__ m2, const float* __restrict__ v2,
    const float* __restrict__ clw, float* __restrict__ ws) {
  int id = blockIdx.x*256 + threadIdx.x;
  if (id < 69984) {                      // w1f: [mc][kw][kh][kdd][o]
    int o   = id % 18;
    int kdd = (id/18) % 3;
    int kh  = (id/54) % 3;
    int kw  = (id/162) % 3;
    int mc  = id/486;
    float s = g1[o] / sqrtf(v1[o] + EPS_);
    ws[OFF_W1F + id] = w1[(o*MC_ + mc)*27 + kh*9 + kw*3 + kdd] * s;
    return;
  }
  id -= 69984;
  if (id < 18) {
    float s = g1[id]/sqrtf(v1[id]+EPS_);
    ws[OFF_B1F + id] = (b1[id]-m1[id])*s + be1[id];
    return;
  }
  id -= 18;
  if (id < 4374) {                       // w2f: [c][tap][i]
    int i = id % 9, tap = (id/9) % 27, c = id/243;
    float s = g2[i]/sqrtf(v2[i]+EPS_);
    ws[OFF_W2F + id] = w2[(i*HID_ + c)*27 + tap] * s;
    return;
  }
  id -= 4374;
  if (id < 9) {
    float s = g2[id]/sqrtf(v2[id]+EPS_);
    ws[OFF_B2F + id] = (b2[id]-m2[id])*s + be2[id];
    return;
  }
  id -= 9;
  if (id < 21600) {                      // clwT: [mc][oc]
    int oc = id % OUT_, mc = id / OUT_;
    ws[OFF_CLWT + id] = clw[oc*MC_ + mc];
  }
}

// ---------------- K3: global attention branch (1x1x1 volume => center taps) ---
__global__ __launch_bounds__(64) void k_ga(
    const float* __restrict__ gw1, const float* __restrict__ gb1,
    const float* __restrict__ gg1, const float* __restrict__ gbe1,
    const float* __restrict__ gm1, const float* __restrict__ gv1,
    const float* __restrict__ gw2, const float* __restrict__ gb2,
    const float* __restrict__ gg2, const float* __restrict__ gbe2,
    const float* __restrict__ gm2, const float* __restrict__ gv2,
    float* __restrict__ ws) {
  __shared__ float gl[B_*HID_];
  int t = threadIdx.x;
  if (t < B_*HID_) {
    int b = t / HID_, j = t % HID_;
    float acc = gb1[j];
    for (int ch = 0; ch < MC_; ch++)
      acc += gw1[(j*MC_ + ch)*27 + 13] * ws[OFF_P + b*MC_ + ch];
    float s = gg1[j]/sqrtf(gv1[j]+EPS_);
    gl[t] = fmaxf((acc - gm1[j])*s + gbe1[j], 0.f);
  }
  __syncthreads();
  if (t < B_*M_) {
    int b = t / M_, i = t % M_;
    float acc = gb2[i];
    for (int j = 0; j < HID_; j++)
      acc += gw2[(i*HID_ + j)*27 + 13] * gl[b*HID_ + j];
    float s = gg2[i]/sqrtf(gv2[i]+EPS_);
    ws[OFF_XG + b*M_ + i] = (acc - gm2[i])*s + gbe2[i];
  }
}

// ---------------- K4: F[b][m][kdd][h][w''][o] = per-(m,kdd) 2D 3x3 conv of x --
__global__ __launch_bounds__(256) void k_F(const float* __restrict__ x,
                                           float* __restrict__ ws) {
  int h0 = blockIdx.x * 4;
  int m  = blockIdx.y;
  int b  = blockIdx.z;
  __shared__ float xt[C_*132*6];        // [c][col+2 (0..131)][hrow 0..5]
  for (int e = threadIdx.x; e < C_*132*6; e += 256) {
    int hh = e % 6;
    int cc = (e/6) % 132;
    int c  = e / 792;
    int row = h0 - 1 + hh;
    int col = cc - 2;
    float v = 0.f;
    if (row >= 0 && row < H_ && col >= 0 && col < W_)
      v = x[(((size_t)(b*C_ + c)*H_ + row)*W_ + col)*M_ + m];
    xt[e] = v;
  }
  __syncthreads();
  const float* w1f = ws + OFF_W1F;
  float* Fb = ws + OFF_F + (size_t)(b*M_ + m)*3*H_*130*20;
  for (int pp = threadIdx.x; pp < 130*18; pp += 256) {
    int o   = pp % 18;
    int wpp = pp / 18;                  // w'' = wpp-1 in [-1,128]
    float acc[3][4] = {};
    for (int c = 0; c < C_; c++) {
      int wb = (m*C_ + c)*486 + o;
      #pragma unroll
      for (int kw = 0; kw < 3; kw++) {
        const float* xp = xt + (c*132 + wpp + kw)*6;   // col = w''+kw-1
        float xv[6];
        #pragma unroll
        for (int q = 0; q < 6; q++) xv[q] = xp[q];
        const float* wp = w1f + wb + kw*162;
        #pragma unroll
        for (int kh = 0; kh < 3; kh++)
          #pragma unroll
          for (int kdd = 0; kdd < 3; kdd++) {
            float wv = wp[kh*54 + kdd*18];
            #pragma unroll
            for (int hh = 0; hh < 4; hh++)
              acc[kdd][hh] += wv * xv[hh + kh];
          }
      }
    }
    #pragma unroll
    for (int kdd = 0; kdd < 3; kdd++)
      #pragma unroll
      for (int hh = 0; hh < 4; hh++)
        Fb[(((size_t)kdd*H_ + (h0+hh))*130 + wpp)*20 + o] = acc[kdd][hh];
  }
}

// ---------------- K5: conv1 = gather-sum of F (+edge fix) + BN bias + ReLU ----
__global__ __launch_bounds__(256) void k_comb1(const float* __restrict__ x,
                                               float* __restrict__ ws) {
  int p = blockIdx.x*256 + threadIdx.x;  // flat point ((b*H+h)*W+w)*9+d
  int d = p % 9;
  int w = (p / 9) % W_;
  int h = (p / (9*W_)) % H_;
  int b = p / (9*W_*H_);
  const float* Fq = ws + OFF_F;
  float acc[18];
  #pragma unroll
  for (int o = 0; o < 18; o++) acc[o] = ws[OFF_B1F + o];
  for (int m = 0; m < M_; m++) {
    int sm = m - 4;
    #pragma unroll
    for (int kdd = 0; kdd < 3; kdd++) {
      int dp = d + kdd - 1;
      if (dp < 0 || dp >= ND_) continue;
      int wg = w + (dp - 4)*sm;
      if (wg < -1 || wg > 128) continue;          // F is zero outside
      const float* Fr = Fq + (((size_t)((b*M_+m)*3 + kdd)*H_ + h)*130 + (wg+1))*20;
      float4 a0 = *(const float4*)(Fr);
      float4 a1 = *(const float4*)(Fr + 4);
      float4 a2 = *(const float4*)(Fr + 8);
      float4 a3 = *(const float4*)(Fr + 12);
      float2 a4 = *(const float2*)(Fr + 16);
      acc[0]+=a0.x; acc[1]+=a0.y; acc[2]+=a0.z; acc[3]+=a0.w;
      acc[4]+=a1.x; acc[5]+=a1.y; acc[6]+=a1.z; acc[7]+=a1.w;
      acc[8]+=a2.x; acc[9]+=a2.y; acc[10]+=a2.z; acc[11]+=a2.w;
      acc[12]+=a3.x; acc[13]+=a3.y; acc[14]+=a3.z; acc[15]+=a3.w;
      acc[16]+=a4.x; acc[17]+=a4.y;
    }
  }
  // w-padding edge correction: conv zero-pads BEFORE the disparity shift.
  if (w == 0 || w == 127) {
    int kwe = (w == 0) ? 0 : 2;
    const float* w1f = ws + OFF_W1F;
    for (int m = 0; m < M_; m++) {
      int sm = m - 4;
      for (int kdd = 0; kdd < 3; kdd++) {
        int dp = d + kdd - 1;
        if (dp < 0 || dp >= ND_) continue;
        int col = w + (dp - 4)*sm + kwe - 1;
        if (col < 0 || col >= W_) continue;
        for (int c = 0; c < C_; c++) {
          const float* wpb = w1f + (m*C_ + c)*486 + kwe*162 + kdd*18;
          for (int kh = 0; kh < 3; kh++) {
            int row = h + kh - 1;
            if (row < 0 || row >= H_) continue;
            float xv = x[(((size_t)(b*C_ + c)*H_ + row)*W_ + col)*M_ + m];
            const float* wp2 = wpb + kh*54;
            #pragma unroll
            for (int o = 0; o < 18; o++) acc[o] -= wp2[o] * xv;
          }
        }
      }
    }
  }
  float2* hb2 = (float2*)(ws + OFF_HBUF + (size_t)p*18);
  #pragma unroll
  for (int q = 0; q < 9; q++)
    hb2[q] = make_float2(fmaxf(acc[2*q], 0.f), fmaxf(acc[2*q+1], 0.f));
}

// ---------------- K6: conv2 (18->9, 3x3x3) + BN + x_g + sigmoid -> wei --------
__global__ __launch_bounds__(576) void k_conv2(float* __restrict__ ws) {
  int w0 = blockIdx.x * 8;
  int h0 = blockIdx.y * 8;
  int b  = blockIdx.z;
  int t  = threadIdx.x;
  int lh = t / 72;
  int lw = (t / 9) % 8;
  int d  = t % 9;
  __shared__ float ht[9900];            // [hh 10][ww 10][dd 11][cc 9]
  const float* hbuf = ws + OFF_HBUF;
  const float* w2f  = ws + OFF_W2F;
  float acc[9] = {};
  for (int c0 = 0; c0 < 18; c0 += 9) {
    __syncthreads();
    for (int e = t; e < 9900; e += 576) {
      int cc = e % 9;
      int dd = (e/9) % 11;
      int ww = (e/99) % 10;
      int hh = e / 990;
      int gh = h0 - 1 + hh, gw = w0 - 1 + ww, gd = dd - 1;
      float v = 0.f;
      if (gh >= 0 && gh < H_ && gw >= 0 && gw < W_ && gd >= 0 && gd < ND_)
        v = hbuf[((size_t)((b*H_ + gh)*W_ + gw)*9 + gd)*18 + c0 + cc];
      ht[e] = v;
    }
    __syncthreads();
    for (int cc = 0; cc < 9; cc++) {
      #pragma unroll
      for (int kh = 0; kh < 3; kh++)
        #pragma unroll
        for (int kw = 0; kw < 3; kw++)
          #pragma unroll
          for (int kdd = 0; kdd < 3; kdd++) {
            float v = ht[(((lh+kh)*10 + (lw+kw))*11 + (d+kdd))*9 + cc];
            const float* wp = w2f + ((c0+cc)*27 + kh*9 + kw*3 + kdd)*9;
            #pragma unroll
            for (int i = 0; i < 9; i++) acc[i] += wp[i] * v;
          }
    }
  }
  int h = h0 + lh, w = w0 + lw;
  float* wei = ws + OFF_WEI + ((size_t)((b*H_ + h)*W_ + w)*9 + d)*9;
  const float* xg = ws + OFF_XG + b*M_;
  #pragma unroll
  for (int i = 0; i < 9; i++) {
    float y = acc[i] + ws[OFF_B2F + i] + xg[i];
    wei[i] = 1.f / (1.f + expf(-y));
  }
}

// ---------------- K7: G[b][h][m][w'][152] = sum_c clw[oc][mc]*x[c,h,w',m] -----
__global__ __launch_bounds__(192) void k_G(const float* __restrict__ x,
                                           const float* __restrict__ ws,
                                           __hip_bfloat16* __restrict__ Gb) {
  int h = blockIdx.x, m = blockIdx.y, b = blockIdx.z;
  int oc = threadIdx.x;
  if (oc >= GOC_) return;
  __hip_bfloat16* Gr = Gb + ((size_t)(b*H_ + h)*M_ + m)*W_*GOC_;
  if (oc >= OUT_) {                     // zero the pad lanes
    for (int wp = 0; wp < W_; wp++) Gr[wp*GOC_ + oc] = __float2bfloat16(0.f);
    return;
  }
  const float* clwT = ws + OFF_CLWT;
  float wreg[C_];
  #pragma unroll
  for (int c = 0; c < C_; c++) wreg[c] = clwT[(m*C_ + c)*OUT_ + oc];
  for (int wp = 0; wp < W_; wp++) {
    float acc = 0.f;
    #pragma unroll
    for (int c = 0; c < C_; c++) {
      float xv = x[(((size_t)(b*C_ + c)*H_ + h)*W_ + wp)*M_ + m];
      acc += wreg[c] * xv;
    }
    Gr[wp*GOC_ + oc] = __float2bfloat16(acc);
  }
}

// ---------------- K8: out = cl_b + sum_m wei[m]*G[h][m][w+s][oc] --------------
// Thread = (w, oc-quad). One ushort4 (4 bf16) load per (m,d); coalesced across
// the wave (lanes cover consecutive ocq then w). acc[9][4] in registers; no LDS.
__global__ __launch_bounds__(256) void k_last(const float* __restrict__ ws,
                                              const __hip_bfloat16* __restrict__ Gb,
                                              const float* __restrict__ clb,
                                              float* __restrict__ out) {
  int h = blockIdx.y;
  int b = blockIdx.z;
  int idx = blockIdx.x*256 + threadIdx.x;   // 0..4863 = w*38 + ocq
  int w   = idx / 38;
  int ocq = idx % 38;
  int oc0 = ocq * 4;

  float acc[9][4];
  #pragma unroll
  for (int j = 0; j < 4; j++) {
    float cb = (oc0 + j < OUT_) ? clb[oc0 + j] : 0.f;
    #pragma unroll
    for (int d = 0; d < 9; d++) acc[d][j] = cb;
  }

  const float* wv = ws + OFF_WEI + (size_t)((b*H_ + h)*W_ + w)*81;
  const __hip_bfloat16* Gh = Gb + (size_t)(b*H_ + h)*M_*W_*GOC_;
  for (int m = 0; m < 9; m++) {
    int sm = m - 4;
    const __hip_bfloat16* Gm = Gh + (size_t)m*W_*GOC_;
    #pragma unroll
    for (int d = 0; d < 9; d++) {
      int wg = w + (d - 4)*sm;
      if (wg < 0 || wg >= W_) continue;
      ushort4 u = *(const ushort4*)(Gm + wg*GOC_ + oc0);
      float wf = wv[d*9 + m];
      acc[d][0] += wf * __uint_as_float(((unsigned)u.x) << 16);
      acc[d][1] += wf * __uint_as_float(((unsigned)u.y) << 16);
      acc[d][2] += wf * __uint_as_float(((unsigned)u.z) << 16);
      acc[d][3] += wf * __uint_as_float(((unsigned)u.w) << 16);
    }
  }

  #pragma unroll
  for (int j = 0; j < 4; j++) {
    int oc = oc0 + j;
    if (oc >= OUT_) break;
    float* op = out + (((size_t)(b*OUT_ + oc)*H_ + h)*W_ + w)*9;
    #pragma unroll
    for (int d = 0; d < 9; d++) op[d] = acc[d][j];
  }
}

extern "C" void kernel_launch(void* const* d_in, const int* in_sizes, int n_in,
                              void* d_out, int out_size, void* d_ws, size_t ws_size,
                              hipStream_t stream) {
  const float* x       = (const float*)d_in[0];
  const float* la_w1   = (const float*)d_in[1];
  const float* la_b1   = (const float*)d_in[2];
  const float* la_g1   = (const float*)d_in[3];
  const float* la_be1  = (const float*)d_in[4];
  const float* la_m1   = (const float*)d_in[5];
  const float* la_v1   = (const float*)d_in[6];
  const float* la_w2   = (const float*)d_in[7];
  const float* la_b2   = (const float*)d_in[8];
  const float* la_g2   = (const float*)d_in[9];
  const float* la_be2  = (const float*)d_in[10];
  const float* la_m2   = (const float*)d_in[11];
  const float* la_v2   = (const float*)d_in[12];
  const float* ga_w1   = (const float*)d_in[13];
  const float* ga_b1   = (const float*)d_in[14];
  const float* ga_g1   = (const float*)d_in[15];
  const float* ga_be1  = (const float*)d_in[16];
  const float* ga_m1   = (const float*)d_in[17];
  const float* ga_v1   = (const float*)d_in[18];
  const float* ga_w2   = (const float*)d_in[19];
  const float* ga_b2   = (const float*)d_in[20];
  const float* ga_g2   = (const float*)d_in[21];
  const float* ga_be2  = (const float*)d_in[22];
  const float* ga_m2   = (const float*)d_in[23];
  const float* ga_v2   = (const float*)d_in[24];
  const float* cl_w    = (const float*)d_in[25];
  const float* cl_b    = (const float*)d_in[26];

  float* ws = (float*)d_ws;
  __hip_bfloat16* Gb = (__hip_bfloat16*)((char*)d_ws + OFF_GB_BYTES);
  float* out = (float*)d_out;

  k_pool  <<<288, 256, 0, stream>>>(x, ws);
  k_repack<<<375, 256, 0, stream>>>(la_w1, la_b1, la_g1, la_be1, la_m1, la_v1,
                                    la_w2, la_b2, la_g2, la_be2, la_m2, la_v2,
                                    cl_w, ws);
  k_ga    <<<1, 64, 0, stream>>>(ga_w1, ga_b1, ga_g1, ga_be1, ga_m1, ga_v1,
                                 ga_w2, ga_b2, ga_g2, ga_be2, ga_m2, ga_v2, ws);
  k_F     <<<dim3(32, 9, 2), 256, 0, stream>>>(x, ws);
  k_comb1 <<<1152, 256, 0, stream>>>(x, ws);
  k_conv2 <<<dim3(16, 16, 2), 576, 0, stream>>>(ws);
  k_G     <<<dim3(128, 9, 2), 192, 0, stream>>>(x, ws, Gb);
  k_last  <<<dim3(19, 128, 2), 256, 0, stream>>>(ws, Gb, cl_b, out);
}

// Round 3
// 1093.039 us; speedup vs baseline: 2.0013x; 1.2891x over previous
//
#include <hip/hip_runtime.h>
#include <hip/hip_bf16.h>
#include <cstddef>

#define B_ 2
#define C_ 16
#define H_ 128
#define W_ 128
#define M_ 9
#define ND_ 9
#define MC_ 144
#define HID_ 18
#define OUT_ 150
#define GOC_ 152          // padded oc stride for G (8B-aligned quads)
#define EPS_ 1e-5f

// ---- workspace layout (float offsets) ----
#define OFF_P     0          // [B][144] pooled means                 (288)
#define OFF_XG    512        // [B][9]  global-attention out          (18)
#define OFF_W1F   1024       // conv1 w, BN1-folded: [mc][kw][kh][kdd][18] (69984)
#define OFF_B1F   71040      // [18]
#define OFF_W2F   71104      // conv2 w, BN2-folded: [c][tap][9]      (4374)
#define OFF_B2F   75520      // [9]
#define OFF_CLWT  75584      // cl_w transposed [mc][150]             (21600)
#define OFF_F     98304      // F[b][m][kdd][h][wpp=130][20pad]       (17,971,200)
#define OFF_HBUF  18069504   // h pre-relu: [b][h][d][w][18]          (5,308,416)
#define OFF_WEI   23377920   // sigmoid attention: [b][h][w][d][9]    (2,654,208)
// G (bf16) overlays F+HBUF: both are dead before k_G runs.
// G[b][h][m][w'][152] = 44,777,472 bf16 = 89.6 MB; ends well before OFF_WEI.
#define OFF_GB_BYTES (98304ull*4ull)

// ---------------- K1: pooled mean of cost volume (global-attn input) ----------
// Split over 8 h-ranges per (b,mc); atomicAdd into P (zeroed by memset).
__global__ __launch_bounds__(256) void k_pool(const float* __restrict__ x,
                                              float* __restrict__ ws) {
  int bid = blockIdx.x;                 // 0..287 = b*144+mc
  int z   = blockIdx.y;                 // 0..7
  int b = bid / MC_, mc = bid % MC_;
  int m = mc / C_, c = mc % C_;
  int sm = m - 4;
  const float* xb = x + (size_t)(b*C_ + c)*H_*W_*M_;
  float acc = 0.f;
  int i0 = z * (H_*W_*ND_/8);
  int i1 = i0 + (H_*W_*ND_/8);
  for (int idx = i0 + (int)threadIdx.x; idx < i1; idx += 256) {
    int w = idx & 127;
    int t = idx >> 7;
    int d = t % 9;
    int h = t / 9;
    int wc = w + (d - 4)*sm;
    if (wc >= 0 && wc < W_) acc += xb[(h*W_ + wc)*M_ + m];
  }
  __shared__ float red[256];
  red[threadIdx.x] = acc;
  __syncthreads();
  for (int s = 128; s > 0; s >>= 1) {
    if ((int)threadIdx.x < s) red[threadIdx.x] += red[threadIdx.x + s];
    __syncthreads();
  }
  if (threadIdx.x == 0)
    atomicAdd(&ws[OFF_P + b*MC_ + mc], red[0] * (1.f/(float)(H_*W_*ND_)));
}

// ---------------- K2: fold BN into conv weights; transpose layouts ------------
__global__ __launch_bounds__(256) void k_repack(
    const float* __restrict__ w1, const float* __restrict__ b1,
    const float* __restrict__ g1, const float* __restrict__ be1,
    const float* __restrict__ m1, const float* __restrict__ v1,
    const float* __restrict__ w2, const float* __restrict__ b2,
    const float* __restrict__ g2, const float* __restrict__ be2,
    const float* __restrict__ m2, const float* __restrict__ v2,
    const float* __restrict__ clw, float* __restrict__ ws) {
  int id = blockIdx.x*256 + threadIdx.x;
  if (id < 69984) {                      // w1f: [mc][kw][kh][kdd][o]
    int o   = id % 18;
    int kdd = (id/18) % 3;
    int kh  = (id/54) % 3;
    int kw  = (id/162) % 3;
    int mc  = id/486;
    float s = g1[o] / sqrtf(v1[o] + EPS_);
    ws[OFF_W1F + id] = w1[(o*MC_ + mc)*27 + kh*9 + kw*3 + kdd] * s;
    return;
  }
  id -= 69984;
  if (id < 18) {
    float s = g1[id]/sqrtf(v1[id]+EPS_);
    ws[OFF_B1F + id] = (b1[id]-m1[id])*s + be1[id];
    return;
  }
  id -= 18;
  if (id < 4374) {                       // w2f: [c][tap][i]
    int i = id % 9, tap = (id/9) % 27, c = id/243;
    float s = g2[i]/sqrtf(v2[i]+EPS_);
    ws[OFF_W2F + id] = w2[(i*HID_ + c)*27 + tap] * s;
    return;
  }
  id -= 4374;
  if (id < 9) {
    float s = g2[id]/sqrtf(v2[id]+EPS_);
    ws[OFF_B2F + id] = (b2[id]-m2[id])*s + be2[id];
    return;
  }
  id -= 9;
  if (id < 21600) {                      // clwT: [mc][oc]
    int oc = id % OUT_, mc = id / OUT_;
    ws[OFF_CLWT + id] = clw[oc*MC_ + mc];
  }
}

// ---------------- K3: global attention branch (1x1x1 volume => center taps) ---
__global__ __launch_bounds__(64) void k_ga(
    const float* __restrict__ gw1, const float* __restrict__ gb1,
    const float* __restrict__ gg1, const float* __restrict__ gbe1,
    const float* __restrict__ gm1, const float* __restrict__ gv1,
    const float* __restrict__ gw2, const float* __restrict__ gb2,
    const float* __restrict__ gg2, const float* __restrict__ gbe2,
    const float* __restrict__ gm2, const float* __restrict__ gv2,
    float* __restrict__ ws) {
  __shared__ float gl[B_*HID_];
  int t = threadIdx.x;
  if (t < B_*HID_) {
    int b = t / HID_, j = t % HID_;
    float acc = gb1[j];
    for (int ch = 0; ch < MC_; ch++)
      acc += gw1[(j*MC_ + ch)*27 + 13] * ws[OFF_P + b*MC_ + ch];
    float s = gg1[j]/sqrtf(gv1[j]+EPS_);
    gl[t] = fmaxf((acc - gm1[j])*s + gbe1[j], 0.f);
  }
  __syncthreads();
  if (t < B_*M_) {
    int b = t / M_, i = t % M_;
    float acc = gb2[i];
    for (int j = 0; j < HID_; j++)
      acc += gw2[(i*HID_ + j)*27 + 13] * gl[b*HID_ + j];
    float s = gg2[i]/sqrtf(gv2[i]+EPS_);
    ws[OFF_XG + b*M_ + i] = (acc - gm2[i])*s + gbe2[i];
  }
}

// ---------------- K4: F[b][m][kdd][h][w''][o] = per-(m,kdd) 2D 3x3 conv of x --
__global__ __launch_bounds__(256) void k_F(const float* __restrict__ x,
                                           float* __restrict__ ws) {
  int h0 = blockIdx.x * 4;
  int m  = blockIdx.y;
  int b  = blockIdx.z;
  __shared__ float xt[C_*132*6];        // [c][col+2 (0..131)][hrow 0..5]
  for (int e = threadIdx.x; e < C_*132*6; e += 256) {
    int hh = e % 6;
    int cc = (e/6) % 132;
    int c  = e / 792;
    int row = h0 - 1 + hh;
    int col = cc - 2;
    float v = 0.f;
    if (row >= 0 && row < H_ && col >= 0 && col < W_)
      v = x[(((size_t)(b*C_ + c)*H_ + row)*W_ + col)*M_ + m];
    xt[e] = v;
  }
  __syncthreads();
  const float* w1f = ws + OFF_W1F;
  float* Fb = ws + OFF_F + (size_t)(b*M_ + m)*3*H_*130*20;
  for (int pp = threadIdx.x; pp < 130*18; pp += 256) {
    int o   = pp % 18;
    int wpp = pp / 18;                  // w'' = wpp-1 in [-1,128]
    float acc[3][4] = {};
    for (int c = 0; c < C_; c++) {
      int wb = (m*C_ + c)*486 + o;
      #pragma unroll
      for (int kw = 0; kw < 3; kw++) {
        const float* xp = xt + (c*132 + wpp + kw)*6;   // col = w''+kw-1
        float xv[6];
        #pragma unroll
        for (int q = 0; q < 6; q++) xv[q] = xp[q];
        const float* wp = w1f + wb + kw*162;
        #pragma unroll
        for (int kh = 0; kh < 3; kh++)
          #pragma unroll
          for (int kdd = 0; kdd < 3; kdd++) {
            float wv = wp[kh*54 + kdd*18];
            #pragma unroll
            for (int hh = 0; hh < 4; hh++)
              acc[kdd][hh] += wv * xv[hh + kh];
          }
      }
    }
    #pragma unroll
    for (int kdd = 0; kdd < 3; kdd++)
      #pragma unroll
      for (int hh = 0; hh < 4; hh++)
        Fb[(((size_t)kdd*H_ + (h0+hh))*130 + wpp)*20 + o] = acc[kdd][hh];
  }
}

// ---------------- K5: conv1 = gather-sum of F (+edge fix) + BN bias + ReLU ----
// Block = (d, h, b), 128 threads = lane<->w. For each (m,kdd) the wave reads a
// contiguous 5 KB F segment (lane stride 80 B) - coalesced. Edge correction
// (w=0/127, conv w-padding applies BEFORE shift) computed cooperatively.
__global__ __launch_bounds__(128) void k_comb1(const float* __restrict__ x,
                                               float* __restrict__ ws) {
  const int d = blockIdx.x;            // 0..8
  const int h = blockIdx.y;
  const int b = blockIdx.z;
  const int w = threadIdx.x;           // 0..127
  const float* Fq = ws + OFF_F;
  float acc[18];
  #pragma unroll
  for (int o = 0; o < 18; o++) acc[o] = ws[OFF_B1F + o];
  for (int m = 0; m < 9; m++) {
    int sm = m - 4;
    #pragma unroll
    for (int kdd = 0; kdd < 3; kdd++) {
      int dp = d + kdd - 1;
      if (dp < 0 || dp >= ND_) continue;          // wave-uniform
      int wg = w + (dp - 4)*sm;
      if (wg < -1 || wg > 128) continue;          // F is zero outside
      const float* Fr = Fq + (((size_t)((b*M_+m)*3 + kdd)*H_ + h)*130 + (wg+1))*20;
      float4 a0 = *(const float4*)(Fr);
      float4 a1 = *(const float4*)(Fr + 4);
      float4 a2 = *(const float4*)(Fr + 8);
      float4 a3 = *(const float4*)(Fr + 12);
      float2 a4 = *(const float2*)(Fr + 16);
      acc[0]+=a0.x; acc[1]+=a0.y; acc[2]+=a0.z; acc[3]+=a0.w;
      acc[4]+=a1.x; acc[5]+=a1.y; acc[6]+=a1.z; acc[7]+=a1.w;
      acc[8]+=a2.x; acc[9]+=a2.y; acc[10]+=a2.z; acc[11]+=a2.w;
      acc[12]+=a3.x; acc[13]+=a3.y; acc[14]+=a3.z; acc[15]+=a3.w;
      acc[16]+=a4.x; acc[17]+=a4.y;
    }
  }
  // cooperative edge correction: 36 lanes compute corr[edge][o] in parallel
  __shared__ float corr[2][18];
  if (threadIdx.x < 36) {
    int edge = threadIdx.x / 18;       // 0 -> w=0 (kw=0 tap), 1 -> w=127 (kw=2)
    int o    = threadIdx.x % 18;
    int we   = edge ? 127 : 0;
    int kwe  = edge ? 2 : 0;
    float s = 0.f;
    for (int m = 0; m < 9; m++) {
      int sm = m - 4;
      for (int kdd = 0; kdd < 3; kdd++) {
        int dp = d + kdd - 1;
        if (dp < 0 || dp >= ND_) continue;
        int col = we + (dp - 4)*sm + kwe - 1;
        if (col < 0 || col >= W_) continue;
        for (int c = 0; c < C_; c++) {
          const float* wpb = ws + OFF_W1F + (m*C_ + c)*486 + kwe*162 + kdd*18 + o;
          #pragma unroll
          for (int kh = 0; kh < 3; kh++) {
            int row = h + kh - 1;
            if (row < 0 || row >= H_) continue;
            s += wpb[kh*54] * x[(((size_t)(b*C_ + c)*H_ + row)*W_ + col)*M_ + m];
          }
        }
      }
    }
    corr[edge][o] = s;
  }
  __syncthreads();
  if (w == 0) {
    #pragma unroll
    for (int o = 0; o < 18; o++) acc[o] -= corr[0][o];
  }
  if (w == 127) {
    #pragma unroll
    for (int o = 0; o < 18; o++) acc[o] -= corr[1][o];
  }
  // store pre-relu->relu, layout [b][h][d][w][18]; lane stride 72 B, dense
  float2* hb2 = (float2*)(ws + OFF_HBUF +
                          (((size_t)(b*H_ + h)*ND_ + d)*W_ + w)*18);
  #pragma unroll
  for (int q = 0; q < 9; q++)
    hb2[q] = make_float2(fmaxf(acc[2*q], 0.f), fmaxf(acc[2*q+1], 0.f));
}

// ---------------- K6: conv2 (18->9, 3x3x3) + BN + x_g + sigmoid -> wei --------
__global__ __launch_bounds__(576) void k_conv2(float* __restrict__ ws) {
  int w0 = blockIdx.x * 8;
  int h0 = blockIdx.y * 8;
  int b  = blockIdx.z;
  int t  = threadIdx.x;
  int lh = t / 72;
  int lw = (t / 9) % 8;
  int d  = t % 9;
  __shared__ float ht[9900];            // [hh 10][ww 10][dd 11][cc 9]
  const float* hbuf = ws + OFF_HBUF;
  const float* w2f  = ws + OFF_W2F;
  float acc[9] = {};
  for (int c0 = 0; c0 < 18; c0 += 9) {
    __syncthreads();
    for (int e = t; e < 9900; e += 576) {
      int cc = e % 9;
      int dd = (e/9) % 11;
      int ww = (e/99) % 10;
      int hh = e / 990;
      int gh = h0 - 1 + hh, gw = w0 - 1 + ww, gd = dd - 1;
      float v = 0.f;
      if (gh >= 0 && gh < H_ && gw >= 0 && gw < W_ && gd >= 0 && gd < ND_)
        v = hbuf[(((size_t)(b*H_ + gh)*ND_ + gd)*W_ + gw)*18 + c0 + cc];
      ht[e] = v;
    }
    __syncthreads();
    for (int cc = 0; cc < 9; cc++) {
      #pragma unroll
      for (int kh = 0; kh < 3; kh++)
        #pragma unroll
        for (int kw = 0; kw < 3; kw++)
          #pragma unroll
          for (int kdd = 0; kdd < 3; kdd++) {
            float v = ht[(((lh+kh)*10 + (lw+kw))*11 + (d+kdd))*9 + cc];
            const float* wp = w2f + ((c0+cc)*27 + kh*9 + kw*3 + kdd)*9;
            #pragma unroll
            for (int i = 0; i < 9; i++) acc[i] += wp[i] * v;
          }
    }
  }
  int h = h0 + lh, w = w0 + lw;
  float* wei = ws + OFF_WEI + ((size_t)((b*H_ + h)*W_ + w)*9 + d)*9;
  const float* xg = ws + OFF_XG + b*M_;
  #pragma unroll
  for (int i = 0; i < 9; i++) {
    float y = acc[i] + ws[OFF_B2F + i] + xg[i];
    wei[i] = 1.f / (1.f + expf(-y));
  }
}

// ---------------- K7: G[b][h][m][w'][152] = sum_c clw[oc][mc]*x[c,h,w',m] -----
// x row staged in LDS once; compute with broadcast float4 LDS reads.
__global__ __launch_bounds__(192) void k_G(const float* __restrict__ x,
                                           const float* __restrict__ ws,
                                           __hip_bfloat16* __restrict__ Gb) {
  int h = blockIdx.x, m = blockIdx.y, b = blockIdx.z;
  __shared__ float xs[C_][W_];          // 8 KB
  for (int e = threadIdx.x; e < C_*W_; e += 192) {
    int c = e >> 7, wp = e & 127;
    xs[c][wp] = x[(((size_t)(b*C_ + c)*H_ + h)*W_ + wp)*M_ + m];
  }
  __syncthreads();
  int oc = threadIdx.x;
  if (oc >= GOC_) return;
  __hip_bfloat16* Gr = Gb + ((size_t)(b*H_ + h)*M_ + m)*W_*GOC_;
  if (oc >= OUT_) {                     // zero the pad lanes
    for (int wp = 0; wp < W_; wp++) Gr[wp*GOC_ + oc] = __float2bfloat16(0.f);
    return;
  }
  const float* clwT = ws + OFF_CLWT;
  float wreg[C_];
  #pragma unroll
  for (int c = 0; c < C_; c++) wreg[c] = clwT[(m*C_ + c)*OUT_ + oc];
  for (int wp0 = 0; wp0 < W_; wp0 += 4) {
    float a0 = 0.f, a1 = 0.f, a2 = 0.f, a3 = 0.f;
    #pragma unroll
    for (int c = 0; c < C_; c++) {
      float4 xv = *(const float4*)&xs[c][wp0];
      a0 += wreg[c]*xv.x; a1 += wreg[c]*xv.y;
      a2 += wreg[c]*xv.z; a3 += wreg[c]*xv.w;
    }
    Gr[(wp0+0)*GOC_ + oc] = __float2bfloat16(a0);
    Gr[(wp0+1)*GOC_ + oc] = __float2bfloat16(a1);
    Gr[(wp0+2)*GOC_ + oc] = __float2bfloat16(a2);
    Gr[(wp0+3)*GOC_ + oc] = __float2bfloat16(a3);
  }
}

// ---------------- K8: out = cl_b + sum_m wei[m]*G[h][m][w+s][oc] --------------
__global__ __launch_bounds__(256) void k_last(const float* __restrict__ ws,
                                              const __hip_bfloat16* __restrict__ Gb,
                                              const float* __restrict__ clb,
                                              float* __restrict__ out) {
  int h = blockIdx.y;
  int b = blockIdx.z;
  int idx = blockIdx.x*256 + threadIdx.x;   // 0..4863 = w*38 + ocq
  int w   = idx / 38;
  int ocq = idx % 38;
  int oc0 = ocq * 4;

  float acc[9][4];
  #pragma unroll
  for (int j = 0; j < 4; j++) {
    float cb = (oc0 + j < OUT_) ? clb[oc0 + j] : 0.f;
    #pragma unroll
    for (int d = 0; d < 9; d++) acc[d][j] = cb;
  }

  const float* wv = ws + OFF_WEI + (size_t)((b*H_ + h)*W_ + w)*81;
  const __hip_bfloat16* Gh = Gb + (size_t)(b*H_ + h)*M_*W_*GOC_;
  for (int m = 0; m < 9; m++) {
    int sm = m - 4;
    const __hip_bfloat16* Gm = Gh + (size_t)m*W_*GOC_;
    #pragma unroll
    for (int d = 0; d < 9; d++) {
      int wg = w + (d - 4)*sm;
      if (wg < 0 || wg >= W_) continue;
      ushort4 u = *(const ushort4*)(Gm + wg*GOC_ + oc0);
      float wf = wv[d*9 + m];
      acc[d][0] += wf * __uint_as_float(((unsigned)u.x) << 16);
      acc[d][1] += wf * __uint_as_float(((unsigned)u.y) << 16);
      acc[d][2] += wf * __uint_as_float(((unsigned)u.z) << 16);
      acc[d][3] += wf * __uint_as_float(((unsigned)u.w) << 16);
    }
  }

  #pragma unroll
  for (int j = 0; j < 4; j++) {
    int oc = oc0 + j;
    if (oc >= OUT_) break;
    float* op = out + (((size_t)(b*OUT_ + oc)*H_ + h)*W_ + w)*9;
    #pragma unroll
    for (int d = 0; d < 9; d++) op[d] = acc[d][j];
  }
}

extern "C" void kernel_launch(void* const* d_in, const int* in_sizes, int n_in,
                              void* d_out, int out_size, void* d_ws, size_t ws_size,
                              hipStream_t stream) {
  const float* x       = (const float*)d_in[0];
  const float* la_w1   = (const float*)d_in[1];
  const float* la_b1   = (const float*)d_in[2];
  const float* la_g1   = (const float*)d_in[3];
  const float* la_be1  = (const float*)d_in[4];
  const float* la_m1   = (const float*)d_in[5];
  const float* la_v1   = (const float*)d_in[6];
  const float* la_w2   = (const float*)d_in[7];
  const float* la_b2   = (const float*)d_in[8];
  const float* la_g2   = (const float*)d_in[9];
  const float* la_be2  = (const float*)d_in[10];
  const float* la_m2   = (const float*)d_in[11];
  const float* la_v2   = (const float*)d_in[12];
  const float* ga_w1   = (const float*)d_in[13];
  const float* ga_b1   = (const float*)d_in[14];
  const float* ga_g1   = (const float*)d_in[15];
  const float* ga_be1  = (const float*)d_in[16];
  const float* ga_m1   = (const float*)d_in[17];
  const float* ga_v1   = (const float*)d_in[18];
  const float* ga_w2   = (const float*)d_in[19];
  const float* ga_b2   = (const float*)d_in[20];
  const float* ga_g2   = (const float*)d_in[21];
  const float* ga_be2  = (const float*)d_in[22];
  const float* ga_m2   = (const float*)d_in[23];
  const float* ga_v2   = (const float*)d_in[24];
  const float* cl_w    = (const float*)d_in[25];
  const float* cl_b    = (const float*)d_in[26];

  float* ws = (float*)d_ws;
  __hip_bfloat16* Gb = (__hip_bfloat16*)((char*)d_ws + OFF_GB_BYTES);
  float* out = (float*)d_out;

  hipMemsetAsync(d_ws, 0, MC_*B_*sizeof(float), stream);   // zero P for atomics
  k_pool  <<<dim3(288, 8), 256, 0, stream>>>(x, ws);
  k_repack<<<375, 256, 0, stream>>>(la_w1, la_b1, la_g1, la_be1, la_m1, la_v1,
                                    la_w2, la_b2, la_g2, la_be2, la_m2, la_v2,
                                    cl_w, ws);
  k_ga    <<<1, 64, 0, stream>>>(ga_w1, ga_b1, ga_g1, ga_be1, ga_m1, ga_v1,
                                 ga_w2, ga_b2, ga_g2, ga_be2, ga_m2, ga_v2, ws);
  k_F     <<<dim3(32, 9, 2), 256, 0, stream>>>(x, ws);
  k_comb1 <<<dim3(9, 128, 2), 128, 0, stream>>>(x, ws);
  k_conv2 <<<dim3(16, 16, 2), 576, 0, stream>>>(ws);
  k_G     <<<dim3(128, 9, 2), 192, 0, stream>>>(x, ws, Gb);
  k_last  <<<dim3(19, 128, 2), 256, 0, stream>>>(ws, Gb, cl_b, out);
}